// Round 5
// baseline (515.890 us; speedup 1.0000x reference)
//
#include <hip/hip_runtime.h>

// ---------------- problem constants ----------------
#define NNODES 200
#define FEATX  2600      // 50*52
#define FEAT   2800      // FEATX + NNODES
#define NC     88        // 88 K-chunks of 32 -> K padded to 2816
#define N1     128

typedef _Float16 f16;
typedef _Float16 f16x8 __attribute__((ext_vector_type(8)));
typedef float    f32x4 __attribute__((ext_vector_type(4)));

// ---------------- workspace byte offsets ----------------
// W1P: 88 chunks x 8KB, fragment-ordered: [chunk][f(8)][lane(64)][8 f16]
//      value = B[k = chunk*32 + (lane>>4)*8 + j][col = f*16 + (lane&15)]
#define W1P_OFF   0u          // 720896
#define W2P_OFF   720896u     // 4 chunks x 8KB = 32768
#define W3P_OFF   753664u     // 4 chunks x 4KB = 16384
#define WG_OFF    770048u     // 200*128 f16 = 51200
#define B1P_OFF   821248u     // 512
#define HW_OFF    821760u     // 32   (end 821792)

__device__ __forceinline__ void gl_lds16(const void* g, void* l) {
  __builtin_amdgcn_global_load_lds(
      (const __attribute__((address_space(1))) unsigned int*)g,
      (__attribute__((address_space(3))) unsigned int*)l, 16, 0, 0);
}

// ============ prepG: 201 flat blocks, no inter-block deps ============
// blocks 0..199: node n -> Wg'[n, 0..127] (f16).  block 200: b1' fold + hw.
__global__ __launch_bounds__(128)
void prepG(const int* __restrict__ esrc, const int* __restrict__ edst,
           const float* __restrict__ emb, const float* __restrict__ gcw,
           const float* __restrict__ gcb, const float* __restrict__ W1,
           const float* __restrict__ b1, char* __restrict__ ws) {
  const int bid = blockIdx.x, tid = threadIdx.x;   // 128 threads
  if (bid == NNODES) {
    float s = 0.f;
    for (int d = 0; d < NNODES; ++d) s += W1[(FEATX + d) * N1 + tid];
    ((float*)(ws + B1P_OFF))[tid] = b1[tid] + gcb[0] * s;
    if (tid < 3) {
      float h = 0.f;
      for (int q = 0; q < 5; ++q) h += emb[tid * 5 + q] * gcw[q];
      ((float*)(ws + HW_OFF))[tid] = h;
    }
    return;
  }
  __shared__ int din[NNODES];
  __shared__ int mdst[128];
  __shared__ int mcnt;
  const int n = bid;
  for (int i = tid; i < NNODES; i += 128) din[i] = 0;
  if (tid == 0) mcnt = 0;
  __syncthreads();
  for (int e = tid; e < 800; e += 128) {
    const int d = edst[e];
    atomicAdd(&din[d], 1);
    if (esrc[e] == n) { const int p = atomicAdd(&mcnt, 1); if (p < 128) mdst[p] = d; }
  }
  __syncthreads();
  const int deg = mcnt > 128 ? 128 : mcnt;
  const float ns = 1.f / sqrtf(fmaxf((float)mcnt, 1.f));
  float acc = 0.f;
  for (int m = 0; m < deg; ++m) {
    const int d = mdst[m];
    const float w = ns / sqrtf(fmaxf((float)din[d], 1.f));
    acc += w * W1[(FEATX + d) * N1 + tid];
  }
  ((f16*)(ws + WG_OFF))[n * N1 + tid] = (f16)acc;
}

// ============ pack: LDS transpose -> fragment-ordered f16 ============
__global__ __launch_bounds__(256)
void pack(const float* __restrict__ W1, const float* __restrict__ W2,
          const float* __restrict__ W3, char* __restrict__ ws) {
  __shared__ __align__(16) float T[32 * 128];   // 16KB
  const int bid = blockIdx.x, tid = threadIdx.x;  // 96 x 256
  const f16* wg = (const f16*)(ws + WG_OFF);
  if (bid < NC) {
    const int k0 = bid * 32;
#pragma unroll
    for (int i = 0; i < 4; ++i) {
      const int p = i * 1024 + tid * 4;
      const int r = p >> 7, c = p & 127;
      const int k = k0 + r;
      float4 v;
      if (k < FEATX) v = *(const float4*)(W1 + (size_t)k * N1 + c);
      else if (k < FEAT) {
        const f16* g = wg + (k - FEATX) * N1 + c;
        v.x = (float)g[0]; v.y = (float)g[1]; v.z = (float)g[2]; v.w = (float)g[3];
      } else { v.x = v.y = v.z = v.w = 0.f; }
      *(float4*)(&T[r * 128 + c]) = v;
    }
    __syncthreads();
    char* dst = ws + W1P_OFF + (size_t)bid * 8192;
    for (int s = tid; s < 512; s += 256) {
      const int f = s >> 6, lx = s & 63;
      const int colb = f * 16 + (lx & 15), kb = (lx >> 4) * 8;
      union { f16x8 v; f16 h[8]; } u;
#pragma unroll
      for (int j = 0; j < 8; ++j) u.h[j] = (f16)T[(kb + j) * 128 + colb];
      *(f16x8*)(dst + f * 1024 + lx * 16) = u.v;
    }
  } else if (bid < 92) {
    const int cc = bid - 88, k0 = cc * 32;
#pragma unroll
    for (int i = 0; i < 4; ++i) {
      const int p = i * 1024 + tid * 4;
      const int r = p >> 7, c = p & 127;
      *(float4*)(&T[r * 128 + c]) = *(const float4*)(W2 + (size_t)(k0 + r) * 128 + c);
    }
    __syncthreads();
    char* dst = ws + W2P_OFF + (size_t)cc * 8192;
    for (int s = tid; s < 512; s += 256) {
      const int f = s >> 6, lx = s & 63;
      const int colb = f * 16 + (lx & 15), kb = (lx >> 4) * 8;
      union { f16x8 v; f16 h[8]; } u;
#pragma unroll
      for (int j = 0; j < 8; ++j) u.h[j] = (f16)T[(kb + j) * 128 + colb];
      *(f16x8*)(dst + f * 1024 + lx * 16) = u.v;
    }
  } else {
    const int cc = bid - 92, k0 = cc * 32;
#pragma unroll
    for (int i = 0; i < 2; ++i) {
      const int p = i * 1024 + tid * 4;
      const int r = p >> 6, c = p & 63;
      *(float4*)(&T[r * 64 + c]) = *(const float4*)(W3 + (size_t)(k0 + r) * 64 + c);
    }
    __syncthreads();
    char* dst = ws + W3P_OFF + (size_t)cc * 4096;
    {
      const int s = tid;
      const int f = s >> 6, lx = s & 63;
      const int colb = f * 16 + (lx & 15), kb = (lx >> 4) * 8;
      union { f16x8 v; f16 h[8]; } u;
#pragma unroll
      for (int j = 0; j < 8; ++j) u.h[j] = (f16)T[(kb + j) * 64 + colb];
      *(f16x8*)(dst + f * 1024 + lx * 16) = u.v;
    }
  }
}

// ============ fused main: 1 wave/block, 32 rows ============
// B (W1P) via global_load_lds into a 4-deep LDS ring (compiler cannot sink it);
// counted s_waitcnt vmcnt(20) per chunk keeps 3 B-chunks + 2 A-tiles in flight.
// A direct-to-register 2 deep. No barriers (single wave).
__global__ __launch_bounds__(64)
void fused_main(const float* __restrict__ x, const int* __restrict__ apps,
                const char* __restrict__ ws, const float* __restrict__ b2,
                const float* __restrict__ b3, const float* __restrict__ W4,
                const float* __restrict__ b4, float* __restrict__ out) {
  __shared__ __align__(16) char lds[32768];   // ring 4 x 8KB; epilogue reuses [0,8K)
  const int l   = threadIdx.x;   // 0..63
  const int blk = blockIdx.x;    // 0..511
  const int lm  = l & 15, lg = l >> 4;
  const int row0 = blk * 32;

  const float* hwv = (const float*)(ws + HW_OFF);
  const float hw0 = hwv[0], hw1 = hwv[1], hw2 = hwv[2];

  const float* xr0 = x + (size_t)(row0 + lm) * FEATX;
  const float* xr1 = x + (size_t)(row0 + 16 + lm) * FEATX;
  const int*   ir0 = apps + (size_t)(row0 + lm) * NNODES;
  const int*   ir1 = apps + (size_t)(row0 + 16 + lm) * NNODES;
  const char*  w1p = ws + W1P_OFF;

  const f32x4 zed = {0.f, 0.f, 0.f, 0.f};
  f32x4 acc[2][8];
#pragma unroll
  for (int rt = 0; rt < 2; ++rt)
#pragma unroll
    for (int f = 0; f < 8; ++f) acc[rt][f] = zed;

  uint4 A0[4], A1[4];
  f16x8 af[2];

  auto issueB = [&](int c) {        // 8 vmem ops, slot keyed by UNclamped c
    const int cc = c > NC - 1 ? NC - 1 : c;
    const char* src = w1p + (size_t)cc * 8192 + l * 16;
    char* dst = lds + (c & 3) * 8192;
#pragma unroll
    for (int f = 0; f < 8; ++f) gl_lds16(src + f * 1024, dst + f * 1024);
  };
  auto issueA = [&](int c, uint4* A) {  // 4 vmem ops, pointer-select (no branch around loads)
    const int k0 = (c > NC - 1 ? NC - 1 : c) * 32 + lg * 8;
    const char *p0, *p1;
    if (k0 + 8 <= FEATX) { p0 = (const char*)(xr0 + k0); p1 = (const char*)(xr1 + k0); }
    else if (k0 < FEAT)  { p0 = (const char*)(ir0 + (k0 - FEATX)); p1 = (const char*)(ir1 + (k0 - FEATX)); }
    else                 { p0 = (const char*)xr0; p1 = (const char*)xr1; }
    A[0] = *(const uint4*)p0; A[1] = *(const uint4*)(p0 + 16);
    A[2] = *(const uint4*)p1; A[3] = *(const uint4*)(p1 + 16);
  };
  auto CV = [&](int c, const uint4* A, f16x8* a2) {
    const int k0 = c * 32 + lg * 8;
#pragma unroll
    for (int rt = 0; rt < 2; ++rt) {
      union { uint4 u[2]; unsigned ui[8]; float f[8]; } d;
      d.u[0] = A[rt * 2]; d.u[1] = A[rt * 2 + 1];
      union { f16x8 v; f16 h[8]; } r;
      if (k0 + 8 <= FEATX) {
#pragma unroll
        for (int j = 0; j < 8; ++j) r.h[j] = (f16)d.f[j];
      } else if (k0 < FEAT) {
#pragma unroll
        for (int j = 0; j < 8; ++j) {
          const unsigned a = d.ui[j];
          r.h[j] = (f16)(a == 0u ? hw0 : (a == 1u ? hw1 : hw2));
        }
      } else {
#pragma unroll
        for (int j = 0; j < 8; ++j) r.h[j] = (f16)0.f;
      }
      a2[rt] = r.v;
    }
  };
  auto MM = [&](const f16x8* a2, const char* bb) {
#pragma unroll
    for (int f = 0; f < 8; ++f) {
      const f16x8 bf = *(const f16x8*)(bb + f * 1024 + l * 16);
      acc[0][f] = __builtin_amdgcn_mfma_f32_16x16x32_f16(a2[0], bf, acc[0][f], 0, 0, 0);
      acc[1][f] = __builtin_amdgcn_mfma_f32_16x16x32_f16(a2[1], bf, acc[1][f], 0, 0, 0);
    }
  };

  // prologue (issue order defines vmcnt bookkeeping): B0,A0,B1,A1,B2 = 32 ops
  issueB(0); issueA(0, A0); issueB(1); issueA(1, A1); issueB(2);
  __builtin_amdgcn_sched_barrier(0);

#pragma unroll 1
  for (int c = 0; c < NC; c += 2) {
    // ---- chunk c (slot A0): drain oldest 12 = B(c)+A(c) ----
    asm volatile("s_waitcnt vmcnt(20)" ::: "memory");
    CV(c, A0, af);
    issueA(c + 2, A0);          // A before B: keeps [.,A,.,A,B] drain pattern valid
    issueB(c + 3);
    __builtin_amdgcn_sched_barrier(0);
    MM(af, lds + (c & 3) * 8192);
    // ---- chunk c+1 (slot A1) ----
    asm volatile("s_waitcnt vmcnt(20)" ::: "memory");
    CV(c + 1, A1, af);
    issueA(c + 3, A1);
    issueB(c + 4);
    __builtin_amdgcn_sched_barrier(0);
    MM(af, lds + ((c + 1) & 3) * 8192);
  }
  asm volatile("s_waitcnt vmcnt(0)" ::: "memory");   // retire clamped tail loads

  // -------- epilogue 1: + b1', softplus -> LDS a1 f16 [32][128] swizzled --------
  const float* b1p = (const float*)(ws + B1P_OFF);
#pragma unroll
  for (int f = 0; f < 8; ++f) {
    const int col = f * 16 + lm;
    const float bb = b1p[col];
#pragma unroll
    for (int rt = 0; rt < 2; ++rt)
#pragma unroll
      for (int r = 0; r < 4; ++r) {
        const int row = rt * 16 + lg * 4 + r;
        float v = acc[rt][f][r] + bb;
        v = fmaxf(v, 0.f) + log1pf(expf(-fabsf(v)));
        *(f16*)(lds + ((row * 256 + col * 2) ^ ((row & 7) << 4))) = (f16)v;
      }
  }

  // -------- GEMM2: a1 @ W2 (packed frags from L2), softplus -> LDS --------
  f32x4 c2[2][8];
#pragma unroll
  for (int rt = 0; rt < 2; ++rt)
#pragma unroll
    for (int f = 0; f < 8; ++f) c2[rt][f] = zed;
  const char* w2p = ws + W2P_OFF;
#pragma unroll
  for (int ks = 0; ks < 4; ++ks) {
    f16x8 bb2[8];
#pragma unroll
    for (int f = 0; f < 8; ++f)
      bb2[f] = *(const f16x8*)(w2p + ks * 8192 + f * 1024 + l * 16);
    f16x8 a2[2];
#pragma unroll
    for (int rt = 0; rt < 2; ++rt) {
      const int row = rt * 16 + lm;
      a2[rt] = *(const f16x8*)(lds + ((row * 256 + ks * 64 + lg * 16) ^ ((row & 7) << 4)));
    }
#pragma unroll
    for (int f = 0; f < 8; ++f) {
      c2[0][f] = __builtin_amdgcn_mfma_f32_16x16x32_f16(a2[0], bb2[f], c2[0][f], 0, 0, 0);
      c2[1][f] = __builtin_amdgcn_mfma_f32_16x16x32_f16(a2[1], bb2[f], c2[1][f], 0, 0, 0);
    }
  }
#pragma unroll
  for (int f = 0; f < 8; ++f) {
    const int col = f * 16 + lm;
    const float bb = b2[col];
#pragma unroll
    for (int rt = 0; rt < 2; ++rt)
#pragma unroll
      for (int r = 0; r < 4; ++r) {
        const int row = rt * 16 + lg * 4 + r;
        float v = c2[rt][f][r] + bb;
        v = fmaxf(v, 0.f) + log1pf(expf(-fabsf(v)));
        *(f16*)(lds + ((row * 256 + col * 2) ^ ((row & 7) << 4))) = (f16)v;
      }
  }

  // -------- GEMM3: a2 @ W3, tanhshrink -> LDS f32 [32][64] swizzled --------
  f32x4 c3[2][4];
#pragma unroll
  for (int rt = 0; rt < 2; ++rt)
#pragma unroll
    for (int f = 0; f < 4; ++f) c3[rt][f] = zed;
  const char* w3p = ws + W3P_OFF;
#pragma unroll
  for (int ks = 0; ks < 4; ++ks) {
    f16x8 bb3[4];
#pragma unroll
    for (int f = 0; f < 4; ++f)
      bb3[f] = *(const f16x8*)(w3p + ks * 4096 + f * 1024 + l * 16);
    f16x8 a3[2];
#pragma unroll
    for (int rt = 0; rt < 2; ++rt) {
      const int row = rt * 16 + lm;
      a3[rt] = *(const f16x8*)(lds + ((row * 256 + ks * 64 + lg * 16) ^ ((row & 7) << 4)));
    }
#pragma unroll
    for (int f = 0; f < 4; ++f) {
      c3[0][f] = __builtin_amdgcn_mfma_f32_16x16x32_f16(a3[0], bb3[f], c3[0][f], 0, 0, 0);
      c3[1][f] = __builtin_amdgcn_mfma_f32_16x16x32_f16(a3[1], bb3[f], c3[1][f], 0, 0, 0);
    }
  }
#pragma unroll
  for (int f = 0; f < 4; ++f) {
    const int col = f * 16 + lm;
    const float bb = b3[col];
#pragma unroll
    for (int rt = 0; rt < 2; ++rt)
#pragma unroll
      for (int r = 0; r < 4; ++r) {
        const int row = rt * 16 + lg * 4 + r;
        const float z = c3[rt][f][r] + bb;
        *(float*)(lds + ((row * 256 + col * 4) ^ ((row & 7) << 4))) = z - tanhf(z);
      }
  }

  // -------- GEMM4 (vector): a3[32x64] @ W4[64x2] + b4, sigmoid --------
  {
    const int row = l >> 1, j = l & 1;
    float s = 0.f;
#pragma unroll
    for (int kk = 0; kk < 16; ++kk) {
      const f32x4 a = *(const f32x4*)(lds + ((row * 256 + kk * 16) ^ ((row & 7) << 4)));
      s += a[0] * W4[(kk * 4 + 0) * 2 + j] + a[1] * W4[(kk * 4 + 1) * 2 + j]
         + a[2] * W4[(kk * 4 + 2) * 2 + j] + a[3] * W4[(kk * 4 + 3) * 2 + j];
    }
    s += b4[j];
    out[(size_t)(row0 + row) * 2 + j] = 1.f / (1.f + expf(-s));
  }
}

// ---------------- launch ----------------
extern "C" void kernel_launch(void* const* d_in, const int* in_sizes, int n_in,
                              void* d_out, int out_size, void* d_ws, size_t ws_size,
                              hipStream_t stream) {
  const float* x    = (const float*)d_in[0];
  const int*   apps = (const int*)d_in[1];
  const int*   esrc = (const int*)d_in[2];
  const int*   edst = (const int*)d_in[3];
  const float* emb  = (const float*)d_in[4];
  const float* gcw  = (const float*)d_in[5];
  const float* gcb  = (const float*)d_in[6];
  const float* W1   = (const float*)d_in[7];
  const float* b1   = (const float*)d_in[8];
  const float* W2   = (const float*)d_in[9];
  const float* b2   = (const float*)d_in[10];
  const float* W3   = (const float*)d_in[11];
  const float* b3   = (const float*)d_in[12];
  const float* W4   = (const float*)d_in[13];
  const float* b4   = (const float*)d_in[14];
  char* ws = (char*)d_ws;
  float* out = (float*)d_out;

  hipLaunchKernelGGL(prepG, dim3(NNODES + 1), dim3(128), 0, stream,
                     esrc, edst, emb, gcw, gcb, W1, b1, ws);
  hipLaunchKernelGGL(pack, dim3(96), dim3(256), 0, stream, W1, W2, W3, ws);
  hipLaunchKernelGGL(fused_main, dim3(512), dim3(64), 0, stream,
                     x, apps, ws, b2, b3, W4, b4, out);
}